// Round 2
// baseline (233.624 us; speedup 1.0000x reference)
//
#include <hip/hip_runtime.h>
#include <hip/hip_bf16.h>

#define BLOCK 256
#define LT 32
#define LB (BLOCK * LT)        // 8192 elements per block
#define K2THREADS 1024
#define SWZ(i) ((i) + ((i) >> 5))   // +1 word pad per 32 words: serial reads -> (t+i)%32 banks

static __device__ __forceinline__ float sigmoidf_(float w) {
    return 1.0f / (1.0f + expf(-w));
}

struct Params { float a; float invReq; float scale; float T0; };

static __device__ __forceinline__ Params compute_params(const float* T_init, const float* wRe,
                                                        const float* wRv, const float* wC) {
    const float DT = 300.0f;
    float R_env  = 0.001f + sigmoidf_(*wRe) * (0.1f - 0.001f);
    float R_vent = 0.001f + sigmoidf_(*wRv) * (0.1f - 0.001f);
    float C_air  = 1.0e5f + sigmoidf_(*wC) * (1.0e7f - 1.0e5f);
    Params p;
    p.invReq = 1.0f / R_env + 1.0f / R_vent;
    p.a      = 1.0f - DT * p.invReq / C_air;
    p.scale  = DT / C_air;
    p.T0     = *T_init;
    return p;
}

// Kogge-Stone inclusive scan of affine pairs (m,s): f(x) = m*x + s, composed low->high.
// On return regs and sm/ss hold the inclusive result. NT must be power of 2 == blockDim.
template<int NT>
static __device__ __forceinline__ void ks_scan(float& m, float& s, float* sm, float* ss, int t) {
    sm[t] = m; ss[t] = s;
    __syncthreads();
    for (int d = 1; d < NT; d <<= 1) {
        float pm = 1.0f, ps = 0.0f;
        bool act = (t >= d);
        if (act) { pm = sm[t - d]; ps = ss[t - d]; }
        __syncthreads();
        if (act) { s = fmaf(m, ps, s); m *= pm; sm[t] = m; ss[t] = s; }
        __syncthreads();
    }
}

// Pass 1: compute b, stash to global (optional), per-block affine partial.
template<bool HAVE_B>
__global__ __launch_bounds__(BLOCK) void k1_partials(
    const float4* __restrict__ x, const float* __restrict__ T_init,
    const float* __restrict__ wRe, const float* __restrict__ wRv, const float* __restrict__ wC,
    float* __restrict__ b_out, float* __restrict__ partials, int M)
{
    __shared__ float lds_b[LB + LB / 32];
    __shared__ float sm[BLOCK], ss[BLOCK];
    Params p = compute_params(T_init, wRe, wRv, wC);
    const int base = blockIdx.x * LB;
    const int t = threadIdx.x;

    for (int j = t; j < LB; j += BLOCK) {
        int g = base + j;
        float b = 0.0f;
        if (g < M) {
            float4 r = x[g];
            b = p.scale * (fmaf(r.x, p.invReq, r.y) + r.z + r.w);
            if (HAVE_B) b_out[g] = b;
        }
        lds_b[SWZ(j)] = b;
    }
    __syncthreads();

    float s = 0.0f;
    const int lb = t * (LT + 1);
    #pragma unroll
    for (int i = 0; i < LT; ++i) s = fmaf(p.a, s, lds_b[lb + i]);

    float a2 = p.a * p.a, a4 = a2 * a2, a8 = a4 * a4, a16 = a8 * a8, a32 = a16 * a16;
    float m = a32;
    ks_scan<BLOCK>(m, s, sm, ss, t);
    if (t == BLOCK - 1) partials[blockIdx.x] = s;   // block total with zero-initial
}

// Pass 2: scan block partials (multiplier a^LB), fold in T_init -> per-block carry.
__global__ __launch_bounds__(K2THREADS) void k2_scan(
    const float* __restrict__ partials, float* __restrict__ carries,
    const float* __restrict__ T_init, const float* __restrict__ wRe,
    const float* __restrict__ wRv, const float* __restrict__ wC, int nblocks)
{
    __shared__ float sm[K2THREADS], ss[K2THREADS];
    Params p = compute_params(T_init, wRe, wRv, wC);
    float aB = p.a;
    #pragma unroll
    for (int i = 0; i < 13; ++i) aB *= aB;   // a^8192 == a^LB
    const int t = threadIdx.x;
    float m = aB;
    float s = (t < nblocks) ? partials[t] : 0.0f;
    ks_scan<K2THREADS>(m, s, sm, ss, t);
    if (t < nblocks) {
        float g = (t == 0) ? p.T0 : fmaf(sm[t - 1], p.T0, ss[t - 1]);
        carries[t] = g;   // T value entering block t
    }
}

// Pass 3: rebuild per-thread carries, serial emit, coalesced store.
template<bool HAVE_B>
__global__ __launch_bounds__(BLOCK) void k3_emit(
    const float4* __restrict__ x, const float* __restrict__ b_in,
    const float* __restrict__ carries, const float* __restrict__ T_init,
    const float* __restrict__ wRe, const float* __restrict__ wRv, const float* __restrict__ wC,
    float* __restrict__ out, int M)
{
    __shared__ float lds_b[LB + LB / 32];
    __shared__ float sm[BLOCK], ss[BLOCK];
    Params p = compute_params(T_init, wRe, wRv, wC);
    const int base = blockIdx.x * LB;
    const int t = threadIdx.x;

    for (int j = t; j < LB; j += BLOCK) {
        int g = base + j;
        float b = 0.0f;
        if (g < M) {
            if (HAVE_B) {
                b = b_in[g];
            } else {
                float4 r = x[g];
                b = p.scale * (fmaf(r.x, p.invReq, r.y) + r.z + r.w);
            }
        }
        lds_b[SWZ(j)] = b;
    }
    __syncthreads();

    // local per-thread partial (zero initial)
    float s = 0.0f;
    const int lb = t * (LT + 1);
    #pragma unroll
    for (int i = 0; i < LT; ++i) s = fmaf(p.a, s, lds_b[lb + i]);

    float a2 = p.a * p.a, a4 = a2 * a2, a8 = a4 * a4, a16 = a8 * a8, a32 = a16 * a16;
    float m = a32;
    ks_scan<BLOCK>(m, s, sm, ss, t);

    // exclusive carry for this thread, applied to the block's entering T
    float me = 1.0f, se = 0.0f;
    if (t > 0) { me = sm[t - 1]; se = ss[t - 1]; }
    float G = carries[blockIdx.x];
    float T = fmaf(me, G, se);

    #pragma unroll
    for (int i = 0; i < LT; ++i) {
        T = fmaf(p.a, T, lds_b[lb + i]);
        lds_b[lb + i] = T;     // overwrite in place (own stripe only)
    }
    __syncthreads();

    for (int j = t; j < LB; j += BLOCK) {
        int g = base + j;
        if (g < M) out[g + 1] = lds_b[SWZ(j)];
    }
    if (blockIdx.x == 0 && t == 0) out[0] = p.T0;
}

extern "C" void kernel_launch(void* const* d_in, const int* in_sizes, int n_in,
                              void* d_out, int out_size, void* d_ws, size_t ws_size,
                              hipStream_t stream)
{
    const float*  T_init = (const float*)d_in[0];
    const float4* x      = (const float4*)d_in[1];
    const float*  wRe    = (const float*)d_in[2];
    // d_in[3] = w_R_int : unused by the reference
    const float*  wRv    = (const float*)d_in[4];
    const float*  wC     = (const float*)d_in[5];
    float* out = (float*)d_out;

    const int N = out_size;        // 8388608
    const int M = N - 1;           // number of recurrence steps
    const int nblocks = (M + LB - 1) / LB;   // 1024

    float* partials = (float*)d_ws;          // [<=1024]
    float* carries  = partials + 1024;       // [<=1024]
    float* b_buf    = carries + 1024;
    const size_t need_b = 8192 + (size_t)M * sizeof(float);
    const bool have_b = (ws_size >= need_b);

    if (have_b) {
        k1_partials<true ><<<nblocks, BLOCK, 0, stream>>>(x, T_init, wRe, wRv, wC, b_buf, partials, M);
    } else {
        k1_partials<false><<<nblocks, BLOCK, 0, stream>>>(x, T_init, wRe, wRv, wC, nullptr, partials, M);
    }
    k2_scan<<<1, K2THREADS, 0, stream>>>(partials, carries, T_init, wRe, wRv, wC, nblocks);
    if (have_b) {
        k3_emit<true ><<<nblocks, BLOCK, 0, stream>>>(x, b_buf, carries, T_init, wRe, wRv, wC, out, M);
    } else {
        k3_emit<false><<<nblocks, BLOCK, 0, stream>>>(x, nullptr, carries, T_init, wRe, wRv, wC, out, M);
    }
}